// Round 6
// baseline (1684.834 us; speedup 1.0000x reference)
//
#include <hip/hip_runtime.h>
#include <hip/hip_bf16.h>
#include <math.h>

#define TILE 16
#define HALO 5
#define TW   26          // TILE + 2*HALO
#define NCH  16
#define NP   40
#define NSEL 16
#define IMG  256

// Ring offsets in the exact order of _prf_offsets(1,4,4):
// p 0..10 : dx=-5, dy=-5..5   (top row)
// p 11..19: dx=-4..4, dy=+5   (right col)
// p 20..30: dx=+5, dy=-5..5   (bottom row)
// p 31..39: dx=-4..4, dy=-5   (left col)
__device__ __forceinline__ constexpr int ring_dx(int p) {
  return (p < 11) ? -5 : (p < 20) ? (p - 15) : (p < 31) ? 5 : (p - 35);
}
__device__ __forceinline__ constexpr int ring_dy(int p) {
  return (p < 11) ? (p - 5) : (p < 20) ? 5 : (p < 31) ? (p - 25) : -5;
}
// positive LDS element offset relative to tile-corner (ty*TW+tx)
__device__ __forceinline__ constexpr int ring_off(int p) {
  return (ring_dx(p) + HALO) * TW + (ring_dy(p) + HALO);
}

__global__ __launch_bounds__(256, 2)
void pkc2d_kernel(const float* __restrict__ x, const float* __restrict__ w,
                  const float* __restrict__ bias, float* __restrict__ out) {
  __shared__ float xs[NCH * TW * TW];   // [c][r][col]
  __shared__ int s_off[NP];

  const int tid = threadIdx.x;
  const int bz = blockIdx.z;
  const int i0 = blockIdx.y * TILE;
  const int j0 = blockIdx.x * TILE;

  if (tid < NP) s_off[tid] = ring_off(tid);

  // ---- stage x tile (with zero halo) into LDS ----
  const float* xb = x + (size_t)bz * NCH * IMG * IMG;
  for (int t = tid; t < NCH * TW * TW; t += 256) {
    int c = t / (TW * TW);
    int rem = t - c * (TW * TW);
    int r = rem / TW;
    int col = rem - r * TW;
    int gi = i0 + r - HALO;
    int gj = j0 + col - HALO;
    float v = 0.0f;
    if ((unsigned)gi < (unsigned)IMG && (unsigned)gj < (unsigned)IMG)
      v = xb[(c * IMG + gi) * IMG + gj];
    xs[t] = v;
  }
  __syncthreads();

  const int tx = tid & (TILE - 1);
  const int ty = tid >> 4;
  const int corner = ty * TW + tx;                 // (dx+5, dy+5) offsets are relative to this
  const int cen = corner + HALO * TW + HALO;

  // center vector
  float xc[NCH];
#pragma unroll
  for (int c = 0; c < NCH; ++c) xc[c] = xs[c * (TW * TW) + cen];

  // ---- keys = np's f32 sim bits: sequential mul-then-add over c (np's
  // strided-axis reduce order -> bit-exact z), exact /16, then sigmoid as
  // discrete f32 steps with a correctly-rounded f32 exp (via f64 exp).
  // The sigmoid's OUTPUT QUANTIZATION is what creates the reference's tie
  // classes (one sim-ulp spans ~10-20 dot-ulps), so it must be applied. ----
  float keys[NP];
#pragma unroll
  for (int p = 0; p < NP; ++p) {
    const int off = ring_off(p);
    float s = 0.0f;
#pragma unroll
    for (int c = 0; c < NCH; ++c)
      s = __fadd_rn(s, __fmul_rn(xs[c * (TW * TW) + corner + off], xc[c]));
    float z = __fmul_rn(s, 0.0625f);               // /16 exact
    float e = (float)exp(-(double)z);              // CR f32 exp via f64
    keys[p] = __fdiv_rn(1.0f, __fadd_rn(1.0f, e)); // 1/(1+e), f32 steps
  }

  // ---- STABLE selection of 16 smallest (ascending, ties -> lower index),
  // matching jnp.argsort's stable=True default / np.argsort(kind='stable') ----
  int sel[NSEL];
#pragma unroll
  for (int n = 0; n < NSEL; ++n) {
    float best = 3.0e38f;
    int bi = 0;
#pragma unroll
    for (int p = 0; p < NP; ++p) {
      bool better = keys[p] < best;   // strict < keeps earliest index on ties
      best = better ? keys[p] : best;
      bi   = better ? p : bi;
    }
    sel[n] = bi;
#pragma unroll
    for (int p = 0; p < NP; ++p)
      keys[p] = (p == bi) ? 3.0e38f : keys[p];   // destroy selected
  }

  int soff[NSEL];
#pragma unroll
  for (int n = 0; n < NSEL; ++n) soff[n] = corner + s_off[sel[n]];

  // ---- conv: out[o] = bias[o] + sum_{c,n} w[o,c,n] * (xc[c] - xr[c,sel[n]]) ----
  const int i = i0 + ty, j = j0 + tx;
  float* outp = out + (size_t)bz * 32 * IMG * IMG + (size_t)i * IMG + j;

  for (int oc = 0; oc < 2; ++oc) {          // runtime loop: 2 chunks of 16 out-channels
    float acc[16];
#pragma unroll
    for (int u = 0; u < 16; ++u) acc[u] = bias[oc * 16 + u];
#pragma unroll
    for (int n = 0; n < NSEL; ++n) {
      float d[NCH];
#pragma unroll
      for (int c = 0; c < NCH; ++c) d[c] = xc[c] - xs[c * (TW * TW) + soff[n]];
      const float* wp = w + (size_t)(oc * 16) * 256 + n;   // w[o][c][n] flat: o*256 + c*16 + n
#pragma unroll
      for (int u = 0; u < 16; ++u) {
#pragma unroll
        for (int c = 0; c < NCH; ++c)
          acc[u] = __fmaf_rn(wp[u * 256 + c * 16], d[c], acc[u]);
      }
    }
#pragma unroll
    for (int u = 0; u < 16; ++u)
      outp[(size_t)(oc * 16 + u) * IMG * IMG] = acc[u];
  }
}

extern "C" void kernel_launch(void* const* d_in, const int* in_sizes, int n_in,
                              void* d_out, int out_size, void* d_ws, size_t ws_size,
                              hipStream_t stream) {
  const float* x = (const float*)d_in[0];
  const float* w = (const float*)d_in[1];
  const float* b = (const float*)d_in[2];
  float* out = (float*)d_out;
  dim3 grid(IMG / TILE, IMG / TILE, 2);
  pkc2d_kernel<<<grid, dim3(256), 0, stream>>>(x, w, b, out);
}

// Round 7
// 754.884 us; speedup vs baseline: 2.2319x; 2.2319x over previous
//
#include <hip/hip_runtime.h>
#include <hip/hip_bf16.h>

#define TILE 16
#define HALO 5
#define TW   26          // TILE + 2*HALO
#define NCH  16
#define NP   40
#define NSEL 16
#define IMG  256

// Ring offsets in the exact order of _prf_offsets(1,4,4):
// p 0..10 : dx=-5, dy=-5..5   (top row)
// p 11..19: dx=-4..4, dy=+5   (right col)
// p 20..30: dx=+5, dy=-5..5   (bottom row)
// p 31..39: dx=-4..4, dy=-5   (left col)
__device__ __forceinline__ constexpr int ring_dx(int p) {
  return (p < 11) ? -5 : (p < 20) ? (p - 15) : (p < 31) ? 5 : (p - 35);
}
__device__ __forceinline__ constexpr int ring_dy(int p) {
  return (p < 11) ? (p - 5) : (p < 20) ? 5 : (p < 31) ? (p - 25) : -5;
}
// positive LDS element offset relative to tile-corner (ty*TW+tx)
__device__ __forceinline__ constexpr int ring_off(int p) {
  return (ring_dx(p) + HALO) * TW + (ring_dy(p) + HALO);
}

// Inline f64 exp (NO libm call -> no ABI spill to scratch).
// Cody-Waite + deg-15 Taylor; rel err ~5e-16, same f32 buckets as CR exp
// except within ~1e-15 of a boundary (expected flips over all keys: ~0.05).
__device__ __forceinline__ float sigmoid_key(float z) {
  double x = -(double)z;
  const double LOG2E = 1.4426950408889634074;
  double t = __dmul_rn(x, LOG2E);
  const double SHIFT = 6755399441055744.0;        // 1.5*2^52: round-to-nearest-even
  double ts = __dadd_rn(t, SHIFT);
  double n = __dsub_rn(ts, SHIFT);
  int ni = (int)n;                                 // exact integer, |n| tiny
  const double LN2_HI = 6.93147180369123816490e-01;
  const double LN2_LO = 1.90821492927058770002e-10;
  double r = __builtin_fma(-n, LN2_HI, x);
  r = __builtin_fma(-n, LN2_LO, r);                // |r| <= 0.34658
  double p =                 7.6471637318198164759e-13;   // 1/15!
  p = __builtin_fma(p, r, 1.1470745597729724714e-11);     // 1/14!
  p = __builtin_fma(p, r, 1.6059043836821614599e-10);     // 1/13!
  p = __builtin_fma(p, r, 2.0876756987868098979e-09);     // 1/12!
  p = __builtin_fma(p, r, 2.5052108385441718775e-08);     // 1/11!
  p = __builtin_fma(p, r, 2.7557319223985890653e-07);     // 1/10!
  p = __builtin_fma(p, r, 2.7557319223985892510e-06);     // 1/9!
  p = __builtin_fma(p, r, 2.4801587301587301566e-05);     // 1/8!
  p = __builtin_fma(p, r, 1.9841269841269841253e-04);     // 1/7!
  p = __builtin_fma(p, r, 1.3888888888888889419e-03);     // 1/6!
  p = __builtin_fma(p, r, 8.3333333333333332177e-03);     // 1/5!
  p = __builtin_fma(p, r, 4.1666666666666664354e-02);     // 1/4!
  p = __builtin_fma(p, r, 1.6666666666666665741e-01);     // 1/3!
  p = __builtin_fma(p, r, 5.0e-01);                       // 1/2!
  p = __builtin_fma(p, r, 1.0);                           // 1/1!
  p = __builtin_fma(p, r, 1.0);                           // 1/0!
  double sc = __longlong_as_double(((long long)(1023 + ni)) << 52);  // 2^n
  float ef = (float)__dmul_rn(p, sc);
  return __fdiv_rn(1.0f, __fadd_rn(1.0f, ef));     // f32 steps, as np
}

__global__ __launch_bounds__(256, 3)
void pkc2d_kernel(const float* __restrict__ x, const float* __restrict__ w,
                  const float* __restrict__ bias, float* __restrict__ out) {
  __shared__ float xs[NCH * TW * TW];   // [c][r][col]
  __shared__ int s_off[NP];

  const int tid = threadIdx.x;
  const int bz = blockIdx.z;
  const int i0 = blockIdx.y * TILE;
  const int j0 = blockIdx.x * TILE;

  if (tid < NP) s_off[tid] = ring_off(tid);

  // ---- stage x tile (with zero halo) into LDS ----
  const float* xb = x + (size_t)bz * NCH * IMG * IMG;
  for (int t = tid; t < NCH * TW * TW; t += 256) {
    int c = t / (TW * TW);
    int rem = t - c * (TW * TW);
    int r = rem / TW;
    int col = rem - r * TW;
    int gi = i0 + r - HALO;
    int gj = j0 + col - HALO;
    float v = 0.0f;
    if ((unsigned)gi < (unsigned)IMG && (unsigned)gj < (unsigned)IMG)
      v = xb[(c * IMG + gi) * IMG + gj];
    xs[t] = v;
  }
  __syncthreads();

  const int tx = tid & (TILE - 1);
  const int ty = tid >> 4;
  const int corner = ty * TW + tx;                 // (dx+5, dy+5) offsets are relative to this
  const int cen = corner + HALO * TW + HALO;

  // center vector
  float xc[NCH];
#pragma unroll
  for (int c = 0; c < NCH; ++c) xc[c] = xs[c * (TW * TW) + cen];

  // ---- keys = np's f32 sim bits: sequential mul-then-add over c (np's
  // strided-axis reduce order -> bit-exact z), exact /16, then sigmoid as
  // discrete f32 steps via inline f64 exp. The sigmoid's output quantization
  // creates the reference's tie classes, so it must be applied. ----
  float keys[NP];
#pragma unroll
  for (int p = 0; p < NP; ++p) {
    const int off = ring_off(p);
    float s = 0.0f;
#pragma unroll
    for (int c = 0; c < NCH; ++c)
      s = __fadd_rn(s, __fmul_rn(xs[c * (TW * TW) + corner + off], xc[c]));
    keys[p] = sigmoid_key(__fmul_rn(s, 0.0625f));
  }

  // ---- STABLE selection of 16 smallest (ascending, ties -> lower index),
  // matching jnp.argsort's stable default ----
  int sel[NSEL];
#pragma unroll
  for (int n = 0; n < NSEL; ++n) {
    float best = 3.0e38f;
    int bi = 0;
#pragma unroll
    for (int p = 0; p < NP; ++p) {
      bool better = keys[p] < best;   // strict < keeps earliest index on ties
      best = better ? keys[p] : best;
      bi   = better ? p : bi;
    }
    sel[n] = bi;
#pragma unroll
    for (int p = 0; p < NP; ++p)
      keys[p] = (p == bi) ? 3.0e38f : keys[p];   // destroy selected
  }

  int soff[NSEL];
#pragma unroll
  for (int n = 0; n < NSEL; ++n) soff[n] = corner + s_off[sel[n]];

  // ---- conv: out[o] = bias[o] + sum_{c,n} w[o,c,n] * (xc[c] - xr[c,sel[n]]) ----
  const int i = i0 + ty, j = j0 + tx;
  float* outp = out + (size_t)bz * 32 * IMG * IMG + (size_t)i * IMG + j;

  for (int oc = 0; oc < 2; ++oc) {          // runtime loop: 2 chunks of 16 out-channels
    float acc[16];
#pragma unroll
    for (int u = 0; u < 16; ++u) acc[u] = bias[oc * 16 + u];
#pragma unroll
    for (int n = 0; n < NSEL; ++n) {
      float d[NCH];
#pragma unroll
      for (int c = 0; c < NCH; ++c) d[c] = xc[c] - xs[c * (TW * TW) + soff[n]];
      const float* wp = w + (size_t)(oc * 16) * 256 + n;   // w[o][c][n] flat: o*256 + c*16 + n
#pragma unroll
      for (int u = 0; u < 16; ++u) {
#pragma unroll
        for (int c = 0; c < NCH; ++c)
          acc[u] = __fmaf_rn(wp[u * 256 + c * 16], d[c], acc[u]);
      }
    }
#pragma unroll
    for (int u = 0; u < 16; ++u)
      outp[(size_t)(oc * 16 + u) * IMG * IMG] = acc[u];
  }
}

extern "C" void kernel_launch(void* const* d_in, const int* in_sizes, int n_in,
                              void* d_out, int out_size, void* d_ws, size_t ws_size,
                              hipStream_t stream) {
  const float* x = (const float*)d_in[0];
  const float* w = (const float*)d_in[1];
  const float* b = (const float*)d_in[2];
  float* out = (float*)d_out;
  dim3 grid(IMG / TILE, IMG / TILE, 2);
  pkc2d_kernel<<<grid, dim3(256), 0, stream>>>(x, w, b, out);
}

// Round 8
// 539.891 us; speedup vs baseline: 3.1207x; 1.3982x over previous
//
#include <hip/hip_runtime.h>
#include <hip/hip_bf16.h>

#define TILE 16
#define HALO 5
#define TW   26          // TILE + 2*HALO
#define NCH  16
#define NP   40
#define NSEL 16
#define IMG  256

// Ring offsets in the exact order of _prf_offsets(1,4,4):
// p 0..10 : dx=-5, dy=-5..5   (top row)
// p 11..19: dx=-4..4, dy=+5   (right col)
// p 20..30: dx=+5, dy=-5..5   (bottom row)
// p 31..39: dx=-4..4, dy=-5   (left col)
__device__ __forceinline__ constexpr int ring_dx(int p) {
  return (p < 11) ? -5 : (p < 20) ? (p - 15) : (p < 31) ? 5 : (p - 35);
}
__device__ __forceinline__ constexpr int ring_dy(int p) {
  return (p < 11) ? (p - 5) : (p < 20) ? 5 : (p < 31) ? (p - 25) : -5;
}
// positive LDS element offset relative to tile-corner (ty*TW+tx)
__device__ __forceinline__ constexpr int ring_off(int p) {
  return (ring_dx(p) + HALO) * TW + (ring_dy(p) + HALO);
}

// Inline f64 exp (NO libm call -> no ABI spill to scratch).
// Cody-Waite + deg-15 Taylor; rel err ~5e-16, same f32 buckets as CR exp
// except within ~1e-15 of a boundary (expected flips over all keys: ~0.05).
__device__ __forceinline__ float sigmoid_key(float z) {
  double x = -(double)z;
  const double LOG2E = 1.4426950408889634074;
  double t = __dmul_rn(x, LOG2E);
  const double SHIFT = 6755399441055744.0;        // 1.5*2^52: round-to-nearest-even
  double ts = __dadd_rn(t, SHIFT);
  double n = __dsub_rn(ts, SHIFT);
  int ni = (int)n;                                 // exact integer, |n| tiny
  const double LN2_HI = 6.93147180369123816490e-01;
  const double LN2_LO = 1.90821492927058770002e-10;
  double r = __builtin_fma(-n, LN2_HI, x);
  r = __builtin_fma(-n, LN2_LO, r);                // |r| <= 0.34658
  double p =                 7.6471637318198164759e-13;   // 1/15!
  p = __builtin_fma(p, r, 1.1470745597729724714e-11);     // 1/14!
  p = __builtin_fma(p, r, 1.6059043836821614599e-10);     // 1/13!
  p = __builtin_fma(p, r, 2.0876756987868098979e-09);     // 1/12!
  p = __builtin_fma(p, r, 2.5052108385441718775e-08);     // 1/11!
  p = __builtin_fma(p, r, 2.7557319223985890653e-07);     // 1/10!
  p = __builtin_fma(p, r, 2.7557319223985892510e-06);     // 1/9!
  p = __builtin_fma(p, r, 2.4801587301587301566e-05);     // 1/8!
  p = __builtin_fma(p, r, 1.9841269841269841253e-04);     // 1/7!
  p = __builtin_fma(p, r, 1.3888888888888889419e-03);     // 1/6!
  p = __builtin_fma(p, r, 8.3333333333333332177e-03);     // 1/5!
  p = __builtin_fma(p, r, 4.1666666666666664354e-02);     // 1/4!
  p = __builtin_fma(p, r, 1.6666666666666665741e-01);     // 1/3!
  p = __builtin_fma(p, r, 5.0e-01);                       // 1/2!
  p = __builtin_fma(p, r, 1.0);                           // 1/1!
  p = __builtin_fma(p, r, 1.0);                           // 1/0!
  double sc = __longlong_as_double(((long long)(1023 + ni)) << 52);  // 2^n
  float ef = (float)__dmul_rn(p, sc);
  return __fdiv_rn(1.0f, __fadd_rn(1.0f, ef));     // f32 steps, as np
}

__global__ __launch_bounds__(256, 2)   // 2 waves/SIMD cap=256 VGPR: room for ~140 live regs, NO spill
void pkc2d_kernel(const float* __restrict__ x, const float* __restrict__ w,
                  const float* __restrict__ bias, float* __restrict__ out) {
  __shared__ float xs[NCH * TW * TW];   // [c][r][col]
  __shared__ int s_off[NP];

  const int tid = threadIdx.x;
  const int bz = blockIdx.z;
  const int i0 = blockIdx.y * TILE;
  const int j0 = blockIdx.x * TILE;

  if (tid < NP) s_off[tid] = ring_off(tid);

  // ---- stage x tile (with zero halo) into LDS ----
  const float* xb = x + (size_t)bz * NCH * IMG * IMG;
  for (int t = tid; t < NCH * TW * TW; t += 256) {
    int c = t / (TW * TW);
    int rem = t - c * (TW * TW);
    int r = rem / TW;
    int col = rem - r * TW;
    int gi = i0 + r - HALO;
    int gj = j0 + col - HALO;
    float v = 0.0f;
    if ((unsigned)gi < (unsigned)IMG && (unsigned)gj < (unsigned)IMG)
      v = xb[(c * IMG + gi) * IMG + gj];
    xs[t] = v;
  }
  __syncthreads();

  const int tx = tid & (TILE - 1);
  const int ty = tid >> 4;
  const int corner = ty * TW + tx;                 // (dx+5, dy+5) offsets are relative to this
  const int cen = corner + HALO * TW + HALO;

  // center vector
  float xc[NCH];
#pragma unroll
  for (int c = 0; c < NCH; ++c) xc[c] = xs[c * (TW * TW) + cen];

  // ---- keys = np's f32 sim bits: sequential mul-then-add over c (np's
  // strided-axis reduce order -> bit-exact z), exact /16, then sigmoid as
  // discrete f32 steps via inline f64 exp. The sigmoid's output quantization
  // creates the reference's tie classes, so it must be applied. ----
  float keys[NP];
#pragma unroll
  for (int p = 0; p < NP; ++p) {
    const int off = ring_off(p);
    float s = 0.0f;
#pragma unroll
    for (int c = 0; c < NCH; ++c)
      s = __fadd_rn(s, __fmul_rn(xs[c * (TW * TW) + corner + off], xc[c]));
    keys[p] = sigmoid_key(__fmul_rn(s, 0.0625f));
  }

  // ---- STABLE selection of 16 smallest (ascending, ties -> lower index),
  // matching jnp.argsort's stable default ----
  int sel[NSEL];
#pragma unroll
  for (int n = 0; n < NSEL; ++n) {
    float best = 3.0e38f;
    int bi = 0;
#pragma unroll
    for (int p = 0; p < NP; ++p) {
      bool better = keys[p] < best;   // strict < keeps earliest index on ties
      best = better ? keys[p] : best;
      bi   = better ? p : bi;
    }
    sel[n] = bi;
#pragma unroll
    for (int p = 0; p < NP; ++p)
      keys[p] = (p == bi) ? 3.0e38f : keys[p];   // destroy selected
  }

  int soff[NSEL];
#pragma unroll
  for (int n = 0; n < NSEL; ++n) soff[n] = corner + s_off[sel[n]];

  // ---- conv: out[o] = bias[o] + sum_{c,n} w[o,c,n] * (xc[c] - xr[c,sel[n]]) ----
  const int i = i0 + ty, j = j0 + tx;
  float* outp = out + (size_t)bz * 32 * IMG * IMG + (size_t)i * IMG + j;

  for (int oc = 0; oc < 2; ++oc) {          // runtime loop: 2 chunks of 16 out-channels
    float acc[16];
#pragma unroll
    for (int u = 0; u < 16; ++u) acc[u] = bias[oc * 16 + u];
#pragma unroll
    for (int n = 0; n < NSEL; ++n) {
      float d[NCH];
#pragma unroll
      for (int c = 0; c < NCH; ++c) d[c] = xc[c] - xs[c * (TW * TW) + soff[n]];
      const float* wp = w + (size_t)(oc * 16) * 256 + n;   // w[o][c][n] flat: o*256 + c*16 + n
#pragma unroll
      for (int u = 0; u < 16; ++u) {
#pragma unroll
        for (int c = 0; c < NCH; ++c)
          acc[u] = __fmaf_rn(wp[u * 256 + c * 16], d[c], acc[u]);
      }
    }
#pragma unroll
    for (int u = 0; u < 16; ++u)
      outp[(size_t)(oc * 16 + u) * IMG * IMG] = acc[u];
  }
}

extern "C" void kernel_launch(void* const* d_in, const int* in_sizes, int n_in,
                              void* d_out, int out_size, void* d_ws, size_t ws_size,
                              hipStream_t stream) {
  const float* x = (const float*)d_in[0];
  const float* w = (const float*)d_in[1];
  const float* b = (const float*)d_in[2];
  float* out = (float*)d_out;
  dim3 grid(IMG / TILE, IMG / TILE, 2);
  pkc2d_kernel<<<grid, dim3(256), 0, stream>>>(x, w, b, out);
}

// Round 9
// 537.955 us; speedup vs baseline: 3.1319x; 1.0036x over previous
//
#include <hip/hip_runtime.h>
#include <hip/hip_bf16.h>

#define TILE 16
#define HALO 5
#define TW   26          // TILE + 2*HALO
#define NCH  16
#define NP   40
#define NSEL 16
#define IMG  256

// Ring offsets in the exact order of _prf_offsets(1,4,4):
// p 0..10 : dx=-5, dy=-5..5   (top row)
// p 11..19: dx=-4..4, dy=+5   (right col)
// p 20..30: dx=+5, dy=-5..5   (bottom row)
// p 31..39: dx=-4..4, dy=-5   (left col)
__device__ __forceinline__ constexpr int ring_dx(int p) {
  return (p < 11) ? -5 : (p < 20) ? (p - 15) : (p < 31) ? 5 : (p - 35);
}
__device__ __forceinline__ constexpr int ring_dy(int p) {
  return (p < 11) ? (p - 5) : (p < 20) ? 5 : (p < 31) ? (p - 25) : -5;
}
// positive LDS element offset relative to tile-corner (ty*TW+tx)
__device__ __forceinline__ constexpr int ring_off(int p) {
  return (ring_dx(p) + HALO) * TW + (ring_dy(p) + HALO);
}

// Inline f64 exp (no libm call). Cody-Waite + deg-15 Taylor; rel err ~5e-16,
// same f32 buckets as correctly-rounded exp except within ~1e-15 of a
// boundary (expected flips over all 5.2M keys: ~0.05).
__device__ __forceinline__ float sigmoid_key(float z) {
  double x = -(double)z;
  const double LOG2E = 1.4426950408889634074;
  double t = __dmul_rn(x, LOG2E);
  const double SHIFT = 6755399441055744.0;        // 1.5*2^52: round-to-nearest-even
  double ts = __dadd_rn(t, SHIFT);
  double n = __dsub_rn(ts, SHIFT);
  int ni = (int)n;                                 // exact small integer
  const double LN2_HI = 6.93147180369123816490e-01;
  const double LN2_LO = 1.90821492927058770002e-10;
  double r = __builtin_fma(-n, LN2_HI, x);
  r = __builtin_fma(-n, LN2_LO, r);                // |r| <= 0.34658
  double p =                 7.6471637318198164759e-13;   // 1/15!
  p = __builtin_fma(p, r, 1.1470745597729724714e-11);     // 1/14!
  p = __builtin_fma(p, r, 1.6059043836821614599e-10);     // 1/13!
  p = __builtin_fma(p, r, 2.0876756987868098979e-09);     // 1/12!
  p = __builtin_fma(p, r, 2.5052108385441718775e-08);     // 1/11!
  p = __builtin_fma(p, r, 2.7557319223985890653e-07);     // 1/10!
  p = __builtin_fma(p, r, 2.7557319223985892510e-06);     // 1/9!
  p = __builtin_fma(p, r, 2.4801587301587301566e-05);     // 1/8!
  p = __builtin_fma(p, r, 1.9841269841269841253e-04);     // 1/7!
  p = __builtin_fma(p, r, 1.3888888888888889419e-03);     // 1/6!
  p = __builtin_fma(p, r, 8.3333333333333332177e-03);     // 1/5!
  p = __builtin_fma(p, r, 4.1666666666666664354e-02);     // 1/4!
  p = __builtin_fma(p, r, 1.6666666666666665741e-01);     // 1/3!
  p = __builtin_fma(p, r, 5.0e-01);                       // 1/2!
  p = __builtin_fma(p, r, 1.0);                           // 1/1!
  p = __builtin_fma(p, r, 1.0);                           // 1/0!
  double sc = __longlong_as_double(((long long)(1023 + ni)) << 52);  // 2^n
  float ef = (float)__dmul_rn(p, sc);
  return __fdiv_rn(1.0f, __fadd_rn(1.0f, ef));     // f32 steps, as np
}

__global__ __launch_bounds__(256, 2)
void pkc2d_kernel(const float* __restrict__ x, const float* __restrict__ w,
                  const float* __restrict__ bias, float* __restrict__ out) {
  __shared__ float xs[NCH * TW * TW];   // [c][r][col]

  const int tid = threadIdx.x;
  const int bz = blockIdx.z;
  const int i0 = blockIdx.y * TILE;
  const int j0 = blockIdx.x * TILE;

  // ---- stage x tile (with zero halo) into LDS ----
  const float* xb = x + (size_t)bz * NCH * IMG * IMG;
  for (int t = tid; t < NCH * TW * TW; t += 256) {
    int c = t / (TW * TW);
    int rem = t - c * (TW * TW);
    int r = rem / TW;
    int col = rem - r * TW;
    int gi = i0 + r - HALO;
    int gj = j0 + col - HALO;
    float v = 0.0f;
    if ((unsigned)gi < (unsigned)IMG && (unsigned)gj < (unsigned)IMG)
      v = xb[(c * IMG + gi) * IMG + gj];
    xs[t] = v;
  }
  __syncthreads();

  const int tx = tid & (TILE - 1);
  const int ty = tid >> 4;
  const int corner = ty * TW + tx;                 // (dx+5, dy+5) offsets are relative to this
  const int cen = corner + HALO * TW + HALO;

  // ---- dots, c-OUTER (keeps only sdot[40]+1 live; per-p order is still
  // sequential c=0..15 mul-then-add => bit-exact same as np reduce) ----
  float keys[NP];
#pragma unroll
  for (int p = 0; p < NP; ++p) keys[p] = 0.0f;
#pragma unroll 1
  for (int c = 0; c < NCH; ++c) {
    const float* xsc = &xs[c * (TW * TW)];
    float xcv = xsc[cen];
#pragma unroll
    for (int p = 0; p < NP; ++p)
      keys[p] = __fadd_rn(keys[p], __fmul_rn(xsc[corner + ring_off(p)], xcv));
  }

  // ---- sigmoid pass: f32 buckets via inline f64 exp. sched_barrier every
  // 4 p's caps concurrent f64 Horner transients (~32 VGPRs) so the
  // long-lived keys[] are never spilled. ----
#pragma unroll
  for (int p = 0; p < NP; ++p) {
    keys[p] = sigmoid_key(__fmul_rn(keys[p], 0.0625f));
    if ((p & 3) == 3) __builtin_amdgcn_sched_barrier(0);
  }

  // ---- STABLE selection of 16 smallest (ascending, ties -> lower index),
  // matching jnp.argsort's stable default ----
  int soff[NSEL];
#pragma unroll
  for (int n = 0; n < NSEL; ++n) {
    float best = 3.0e38f;
    int bi = 0;
#pragma unroll
    for (int p = 0; p < NP; ++p) {
      bool better = keys[p] < best;   // strict < keeps earliest index on ties
      best = better ? keys[p] : best;
      bi   = better ? p : bi;
    }
    soff[n] = bi;
#pragma unroll
    for (int p = 0; p < NP; ++p)
      keys[p] = (p == bi) ? 3.0e38f : keys[p];   // destroy selected
  }
  // convert ring index -> LDS offset (table is tiny; compute inline)
#pragma unroll
  for (int n = 0; n < NSEL; ++n) {
    int b = soff[n];
    int dx = (b < 11) ? -5 : (b < 20) ? (b - 15) : (b < 31) ? 5 : (b - 35);
    int dy = (b < 11) ? (b - 5) : (b < 20) ? 5 : (b < 31) ? (b - 25) : -5;
    soff[n] = corner + (dx + HALO) * TW + (dy + HALO);
  }

  // center vector (loaded now, after keys are dead)
  float xc[NCH];
#pragma unroll
  for (int c = 0; c < NCH; ++c) xc[c] = xs[c * (TW * TW) + cen];

  // ---- conv: out[o] = bias[o] + sum_{c,n} w[o,c,n] * (xc[c] - xr[c,sel[n]]) ----
  const int i = i0 + ty, j = j0 + tx;
  float* outp = out + (size_t)bz * 32 * IMG * IMG + (size_t)i * IMG + j;

  for (int oc = 0; oc < 2; ++oc) {          // runtime loop: 2 chunks of 16 out-channels
    float acc[16];
#pragma unroll
    for (int u = 0; u < 16; ++u) acc[u] = bias[oc * 16 + u];
#pragma unroll
    for (int n = 0; n < NSEL; ++n) {
      float d[NCH];
#pragma unroll
      for (int c = 0; c < NCH; ++c) d[c] = xc[c] - xs[c * (TW * TW) + soff[n]];
      const float* wp = w + (size_t)(oc * 16) * 256 + n;   // w[o][c][n] flat: o*256 + c*16 + n
#pragma unroll
      for (int u = 0; u < 16; ++u) {
#pragma unroll
        for (int c = 0; c < NCH; ++c)
          acc[u] = __fmaf_rn(wp[u * 256 + c * 16], d[c], acc[u]);
      }
    }
#pragma unroll
    for (int u = 0; u < 16; ++u)
      outp[(size_t)(oc * 16 + u) * IMG * IMG] = acc[u];
  }
}

extern "C" void kernel_launch(void* const* d_in, const int* in_sizes, int n_in,
                              void* d_out, int out_size, void* d_ws, size_t ws_size,
                              hipStream_t stream) {
  const float* x = (const float*)d_in[0];
  const float* w = (const float*)d_in[1];
  const float* b = (const float*)d_in[2];
  float* out = (float*)d_out;
  dim3 grid(IMG / TILE, IMG / TILE, 2);
  pkc2d_kernel<<<grid, dim3(256), 0, stream>>>(x, w, b, out);
}

// Round 10
// 236.526 us; speedup vs baseline: 7.1232x; 2.2744x over previous
//
#include <hip/hip_runtime.h>
#include <hip/hip_bf16.h>

#define TILE 16
#define HALO 5
#define TW   26          // TILE + 2*HALO
#define NCH  16
#define NP   40
#define NSEL 16
#define IMG  256

// Ring offsets in the exact order of _prf_offsets(1,4,4):
// p 0..10 : dx=-5, dy=-5..5   (top row)
// p 11..19: dx=-4..4, dy=+5   (right col)
// p 20..30: dx=+5, dy=-5..5   (bottom row)
// p 31..39: dx=-4..4, dy=-5   (left col)
__device__ __forceinline__ constexpr int ring_dx(int p) {
  return (p < 11) ? -5 : (p < 20) ? (p - 15) : (p < 31) ? 5 : (p - 35);
}
__device__ __forceinline__ constexpr int ring_dy(int p) {
  return (p < 11) ? (p - 5) : (p < 20) ? 5 : (p < 31) ? (p - 25) : -5;
}
// positive LDS element offset relative to tile-corner (ty*TW+tx)
__device__ __forceinline__ constexpr int ring_off(int p) {
  return (ring_dx(p) + HALO) * TW + (ring_dy(p) + HALO);
}

// Inline f64 exp (no libm call). Cody-Waite + deg-15 Taylor; rel err ~5e-16,
// same f32 buckets as correctly-rounded exp except within ~1e-15 of a
// boundary (expected flips over all 5.2M keys: ~0.05).
__device__ __forceinline__ float sigmoid_key(float z) {
  double x = -(double)z;
  const double LOG2E = 1.4426950408889634074;
  double t = __dmul_rn(x, LOG2E);
  const double SHIFT = 6755399441055744.0;        // 1.5*2^52: round-to-nearest-even
  double ts = __dadd_rn(t, SHIFT);
  double n = __dsub_rn(ts, SHIFT);
  int ni = (int)n;                                 // exact small integer
  const double LN2_HI = 6.93147180369123816490e-01;
  const double LN2_LO = 1.90821492927058770002e-10;
  double r = __builtin_fma(-n, LN2_HI, x);
  r = __builtin_fma(-n, LN2_LO, r);                // |r| <= 0.34658
  double p =                 7.6471637318198164759e-13;   // 1/15!
  p = __builtin_fma(p, r, 1.1470745597729724714e-11);     // 1/14!
  p = __builtin_fma(p, r, 1.6059043836821614599e-10);     // 1/13!
  p = __builtin_fma(p, r, 2.0876756987868098979e-09);     // 1/12!
  p = __builtin_fma(p, r, 2.5052108385441718775e-08);     // 1/11!
  p = __builtin_fma(p, r, 2.7557319223985890653e-07);     // 1/10!
  p = __builtin_fma(p, r, 2.7557319223985892510e-06);     // 1/9!
  p = __builtin_fma(p, r, 2.4801587301587301566e-05);     // 1/8!
  p = __builtin_fma(p, r, 1.9841269841269841253e-04);     // 1/7!
  p = __builtin_fma(p, r, 1.3888888888888889419e-03);     // 1/6!
  p = __builtin_fma(p, r, 8.3333333333333332177e-03);     // 1/5!
  p = __builtin_fma(p, r, 4.1666666666666664354e-02);     // 1/4!
  p = __builtin_fma(p, r, 1.6666666666666665741e-01);     // 1/3!
  p = __builtin_fma(p, r, 5.0e-01);                       // 1/2!
  p = __builtin_fma(p, r, 1.0);                           // 1/1!
  p = __builtin_fma(p, r, 1.0);                           // 1/0!
  double sc = __longlong_as_double(((long long)(1023 + ni)) << 52);  // 2^n
  float ef = (float)__dmul_rn(p, sc);
  return __fdiv_rn(1.0f, __fadd_rn(1.0f, ef));     // f32 steps, as np
}

__global__ __launch_bounds__(256, 2)
void pkc2d_kernel(const float* __restrict__ x, const float* __restrict__ w,
                  const float* __restrict__ bias, float* __restrict__ out) {
  __shared__ float xs[NCH * TW * TW];   // [c][r][col]

  const int tid = threadIdx.x;
  const int bz = blockIdx.z;
  const int i0 = blockIdx.y * TILE;
  const int j0 = blockIdx.x * TILE;

  // ---- stage x tile (with zero halo) into LDS ----
  const float* xb = x + (size_t)bz * NCH * IMG * IMG;
  for (int t = tid; t < NCH * TW * TW; t += 256) {
    int c = t / (TW * TW);
    int rem = t - c * (TW * TW);
    int r = rem / TW;
    int col = rem - r * TW;
    int gi = i0 + r - HALO;
    int gj = j0 + col - HALO;
    float v = 0.0f;
    if ((unsigned)gi < (unsigned)IMG && (unsigned)gj < (unsigned)IMG)
      v = xb[(c * IMG + gi) * IMG + gj];
    xs[t] = v;
  }
  __syncthreads();

  const int tx = tid & (TILE - 1);
  const int ty = tid >> 4;
  const int corner = ty * TW + tx;                 // (dx+5, dy+5) offsets are relative to this
  const int cen = corner + HALO * TW + HALO;

  // ---- dots, c-OUTER (keeps only keys[40]+1 live; per-p order is still
  // sequential c=0..15 mul-then-add => bit-exact same as np reduce) ----
  float keys[NP];
#pragma unroll
  for (int p = 0; p < NP; ++p) keys[p] = 0.0f;
#pragma unroll 1
  for (int c = 0; c < NCH; ++c) {
    const float* xsc = &xs[c * (TW * TW)];
    float xcv = xsc[cen];
#pragma unroll
    for (int p = 0; p < NP; ++p)
      keys[p] = __fadd_rn(keys[p], __fmul_rn(xsc[corner + ring_off(p)], xcv));
  }

  // ---- sigmoid pass: f32 buckets via inline f64 exp ----
#pragma unroll
  for (int p = 0; p < NP; ++p) {
    keys[p] = sigmoid_key(__fmul_rn(keys[p], 0.0625f));
    if ((p & 3) == 3) __builtin_amdgcn_sched_barrier(0);
  }

  // ---- STABLE selection of 16 smallest (ascending, ties -> lower index),
  // matching jnp.argsort's stable default ----
  int soff[NSEL];
#pragma unroll
  for (int n = 0; n < NSEL; ++n) {
    float best = 3.0e38f;
    int bi = 0;
#pragma unroll
    for (int p = 0; p < NP; ++p) {
      bool better = keys[p] < best;   // strict < keeps earliest index on ties
      best = better ? keys[p] : best;
      bi   = better ? p : bi;
    }
    soff[n] = bi;
#pragma unroll
    for (int p = 0; p < NP; ++p)
      keys[p] = (p == bi) ? 3.0e38f : keys[p];   // destroy selected
  }
  // convert ring index -> LDS offset
#pragma unroll
  for (int n = 0; n < NSEL; ++n) {
    int b = soff[n];
    int dx = (b < 11) ? -5 : (b < 20) ? (b - 15) : (b < 31) ? 5 : (b - 35);
    int dy = (b < 11) ? (b - 5) : (b < 20) ? 5 : (b < 31) ? (b - 25) : -5;
    soff[n] = corner + (dx + HALO) * TW + (dy + HALO);
  }

  // ---- conv, c-outer with float4 w loads:
  // out[o] = bias[o] + sum_{c,n} w[o,c,n] * (xc[c] - xr[c,sel[n]])
  // w[o][c][n] flat: o*256 + c*16 + n, n contiguous -> 4x dwordx4 per (o,c).
  // 2048 vec4 loads/thread instead of 8192 scalar loads. ----
  const int i = i0 + ty, j = j0 + tx;
  float* outp = out + (size_t)bz * 32 * IMG * IMG + (size_t)i * IMG + j;

  float acc[32];
#pragma unroll
  for (int u = 0; u < 32; ++u) acc[u] = bias[u];

#pragma unroll 1
  for (int c = 0; c < NCH; ++c) {
    const float* xsc = &xs[c * (TW * TW)];
    float xcv = xsc[cen];
    float dn[NSEL];
#pragma unroll
    for (int n = 0; n < NSEL; ++n) dn[n] = xcv - xsc[soff[n]];
    const float* wc = w + c * 16;           // wc[o*256 + n]
#pragma unroll
    for (int u = 0; u < 32; ++u) {
      const float* wu = wc + u * 256;
      float4 w0 = *(const float4*)(wu + 0);
      float4 w1 = *(const float4*)(wu + 4);
      float4 w2 = *(const float4*)(wu + 8);
      float4 w3 = *(const float4*)(wu + 12);
      float a = acc[u];
      a = __fmaf_rn(w0.x, dn[0],  a);
      a = __fmaf_rn(w0.y, dn[1],  a);
      a = __fmaf_rn(w0.z, dn[2],  a);
      a = __fmaf_rn(w0.w, dn[3],  a);
      a = __fmaf_rn(w1.x, dn[4],  a);
      a = __fmaf_rn(w1.y, dn[5],  a);
      a = __fmaf_rn(w1.z, dn[6],  a);
      a = __fmaf_rn(w1.w, dn[7],  a);
      a = __fmaf_rn(w2.x, dn[8],  a);
      a = __fmaf_rn(w2.y, dn[9],  a);
      a = __fmaf_rn(w2.z, dn[10], a);
      a = __fmaf_rn(w2.w, dn[11], a);
      a = __fmaf_rn(w3.x, dn[12], a);
      a = __fmaf_rn(w3.y, dn[13], a);
      a = __fmaf_rn(w3.z, dn[14], a);
      a = __fmaf_rn(w3.w, dn[15], a);
      acc[u] = a;
    }
  }

#pragma unroll
  for (int u = 0; u < 32; ++u)
    outp[(size_t)u * IMG * IMG] = acc[u];
}

extern "C" void kernel_launch(void* const* d_in, const int* in_sizes, int n_in,
                              void* d_out, int out_size, void* d_ws, size_t ws_size,
                              hipStream_t stream) {
  const float* x = (const float*)d_in[0];
  const float* w = (const float*)d_in[1];
  const float* b = (const float*)d_in[2];
  float* out = (float*)d_out;
  dim3 grid(IMG / TILE, IMG / TILE, 2);
  pkc2d_kernel<<<grid, dim3(256), 0, stream>>>(x, w, b, out);
}

// Round 12
// 173.440 us; speedup vs baseline: 9.7142x; 1.3637x over previous
//
#include <hip/hip_runtime.h>
#include <hip/hip_bf16.h>

#define TILE 16
#define HALO 5
#define TW   26          // TILE + 2*HALO
#define NCH  16
#define NP   40
#define NSEL 16
#define IMG  256
#define WSZ  (32 * 256)  // 32 oc x (16 c x 16 n) floats = 32 KB

// Ring offsets in the exact order of _prf_offsets(1,4,4):
__device__ __forceinline__ constexpr int ring_dx(int p) {
  return (p < 11) ? -5 : (p < 20) ? (p - 15) : (p < 31) ? 5 : (p - 35);
}
__device__ __forceinline__ constexpr int ring_dy(int p) {
  return (p < 11) ? (p - 5) : (p < 20) ? 5 : (p < 31) ? (p - 25) : -5;
}
__device__ __forceinline__ constexpr int ring_off(int p) {
  return (ring_dx(p) + HALO) * TW + (ring_dy(p) + HALO);
}

// Inline f64 exp (no libm call). Cody-Waite + deg-15 Taylor; rel err ~5e-16,
// same f32 buckets as correctly-rounded exp except within ~1e-15 of a
// boundary (expected flips over all 5.2M keys: ~0.05).
__device__ __forceinline__ float sigmoid_key(float z) {
  double x = -(double)z;
  const double LOG2E = 1.4426950408889634074;
  double t = __dmul_rn(x, LOG2E);
  const double SHIFT = 6755399441055744.0;        // 1.5*2^52: round-to-nearest-even
  double ts = __dadd_rn(t, SHIFT);
  double n = __dsub_rn(ts, SHIFT);
  int ni = (int)n;                                 // exact small integer
  const double LN2_HI = 6.93147180369123816490e-01;
  const double LN2_LO = 1.90821492927058770002e-10;
  double r = __builtin_fma(-n, LN2_HI, x);
  r = __builtin_fma(-n, LN2_LO, r);                // |r| <= 0.34658
  double p =                 7.6471637318198164759e-13;   // 1/15!
  p = __builtin_fma(p, r, 1.1470745597729724714e-11);     // 1/14!
  p = __builtin_fma(p, r, 1.6059043836821614599e-10);     // 1/13!
  p = __builtin_fma(p, r, 2.0876756987868098979e-09);     // 1/12!
  p = __builtin_fma(p, r, 2.5052108385441718775e-08);     // 1/11!
  p = __builtin_fma(p, r, 2.7557319223985890653e-07);     // 1/10!
  p = __builtin_fma(p, r, 2.7557319223985892510e-06);     // 1/9!
  p = __builtin_fma(p, r, 2.4801587301587301566e-05);     // 1/8!
  p = __builtin_fma(p, r, 1.9841269841269841253e-04);     // 1/7!
  p = __builtin_fma(p, r, 1.3888888888888889419e-03);     // 1/6!
  p = __builtin_fma(p, r, 8.3333333333333332177e-03);     // 1/5!
  p = __builtin_fma(p, r, 4.1666666666666664354e-02);     // 1/4!
  p = __builtin_fma(p, r, 1.6666666666666665741e-01);     // 1/3!
  p = __builtin_fma(p, r, 5.0e-01);                       // 1/2!
  p = __builtin_fma(p, r, 1.0);                           // 1/1!
  p = __builtin_fma(p, r, 1.0);                           // 1/0!
  double sc = __longlong_as_double(((long long)(1023 + ni)) << 52);  // 2^n
  float ef = (float)__dmul_rn(p, sc);
  return __fdiv_rn(1.0f, __fadd_rn(1.0f, ef));     // f32 steps, as np
}

__global__ __launch_bounds__(256, 2)
void pkc2d_kernel(const float* __restrict__ x, const float* __restrict__ w,
                  const float* __restrict__ bias, float* __restrict__ out) {
  __shared__ float xs[NCH * TW * TW];   // [c][r][col] 43.3 KB
  __shared__ float ws[WSZ];             // w[o][c][n] flat copy, 32 KB

  const int tid = threadIdx.x;
  const int bz = blockIdx.z;
  const int i0 = blockIdx.y * TILE;
  const int j0 = blockIdx.x * TILE;

  // ---- stage w into LDS (coalesced float4, 8 per thread) ----
  {
    const float4* wsrc = (const float4*)w;
    float4* wdst = (float4*)ws;
#pragma unroll
    for (int q = 0; q < WSZ / 4 / 256; ++q)       // 8 iters
      wdst[q * 256 + tid] = wsrc[q * 256 + tid];
  }

  // ---- stage x tile (with zero halo) into LDS ----
  const float* xb = x + (size_t)bz * NCH * IMG * IMG;
  for (int t = tid; t < NCH * TW * TW; t += 256) {
    int c = t / (TW * TW);
    int rem = t - c * (TW * TW);
    int r = rem / TW;
    int col = rem - r * TW;
    int gi = i0 + r - HALO;
    int gj = j0 + col - HALO;
    float v = 0.0f;
    if ((unsigned)gi < (unsigned)IMG && (unsigned)gj < (unsigned)IMG)
      v = xb[(c * IMG + gi) * IMG + gj];
    xs[t] = v;
  }
  __syncthreads();

  const int tx = tid & (TILE - 1);
  const int ty = tid >> 4;
  const int corner = ty * TW + tx;                 // (dx+5, dy+5) offsets relative to this
  const int cen = corner + HALO * TW + HALO;

  // ---- dots, c-OUTER (bit-exact np reduce order per p) ----
  float keys[NP];
#pragma unroll
  for (int p = 0; p < NP; ++p) keys[p] = 0.0f;
#pragma unroll 1
  for (int c = 0; c < NCH; ++c) {
    const float* xsc = &xs[c * (TW * TW)];
    float xcv = xsc[cen];
#pragma unroll
    for (int p = 0; p < NP; ++p)
      keys[p] = __fadd_rn(keys[p], __fmul_rn(xsc[corner + ring_off(p)], xcv));
  }

  // ---- sigmoid pass: f32 buckets via inline f64 exp ----
#pragma unroll
  for (int p = 0; p < NP; ++p) {
    keys[p] = sigmoid_key(__fmul_rn(keys[p], 0.0625f));
    if ((p & 3) == 3) __builtin_amdgcn_sched_barrier(0);
  }

  // ---- STABLE selection of 16 smallest (ties -> lower index) ----
  int soff[NSEL];
#pragma unroll
  for (int n = 0; n < NSEL; ++n) {
    float best = 3.0e38f;
    int bi = 0;
#pragma unroll
    for (int p = 0; p < NP; ++p) {
      bool better = keys[p] < best;   // strict < keeps earliest index on ties
      best = better ? keys[p] : best;
      bi   = better ? p : bi;
    }
    soff[n] = bi;
#pragma unroll
    for (int p = 0; p < NP; ++p)
      keys[p] = (p == bi) ? 3.0e38f : keys[p];   // destroy selected
  }
#pragma unroll
  for (int n = 0; n < NSEL; ++n) {
    int b = soff[n];
    int dx = (b < 11) ? -5 : (b < 20) ? (b - 15) : (b < 31) ? 5 : (b - 35);
    int dy = (b < 11) ? (b - 5) : (b < 20) ? 5 : (b < 31) ? (b - 25) : -5;
    soff[n] = corner + (dx + HALO) * TW + (dy + HALO);
  }

  // ---- conv, c-outer, w from LDS (uniform-addr ds_read_b128 = broadcast,
  // conflict-free); unroll 2 gives two independent load groups in flight ----
  const int i = i0 + ty, j = j0 + tx;
  float* outp = out + (size_t)bz * 32 * IMG * IMG + (size_t)i * IMG + j;

  float acc[32];
#pragma unroll
  for (int u = 0; u < 32; ++u) acc[u] = bias[u];

#pragma unroll 2
  for (int c = 0; c < NCH; ++c) {
    const float* xsc = &xs[c * (TW * TW)];
    float xcv = xsc[cen];
    float dn[NSEL];
#pragma unroll
    for (int n = 0; n < NSEL; ++n) dn[n] = xcv - xsc[soff[n]];
    const float* wc = ws + c * 16;          // ws[u*256 + c*16 + n]
#pragma unroll
    for (int u = 0; u < 32; ++u) {
      const float* wu = wc + u * 256;
      float4 w0 = *(const float4*)(wu + 0);
      float4 w1 = *(const float4*)(wu + 4);
      float4 w2 = *(const float4*)(wu + 8);
      float4 w3 = *(const float4*)(wu + 12);
      float a = acc[u];
      a = __fmaf_rn(w0.x, dn[0],  a);
      a = __fmaf_rn(w0.y, dn[1],  a);
      a = __fmaf_rn(w0.z, dn[2],  a);
      a = __fmaf_rn(w0.w, dn[3],  a);
      a = __fmaf_rn(w1.x, dn[4],  a);
      a = __fmaf_rn(w1.y, dn[5],  a);
      a = __fmaf_rn(w1.z, dn[6],  a);
      a = __fmaf_rn(w1.w, dn[7],  a);
      a = __fmaf_rn(w2.x, dn[8],  a);
      a = __fmaf_rn(w2.y, dn[9],  a);
      a = __fmaf_rn(w2.z, dn[10], a);
      a = __fmaf_rn(w2.w, dn[11], a);
      a = __fmaf_rn(w3.x, dn[12], a);
      a = __fmaf_rn(w3.y, dn[13], a);
      a = __fmaf_rn(w3.z, dn[14], a);
      a = __fmaf_rn(w3.w, dn[15], a);
      acc[u] = a;
    }
  }

#pragma unroll
  for (int u = 0; u < 32; ++u)
    outp[(size_t)u * IMG * IMG] = acc[u];
}

extern "C" void kernel_launch(void* const* d_in, const int* in_sizes, int n_in,
                              void* d_out, int out_size, void* d_ws, size_t ws_size,
                              hipStream_t stream) {
  const float* x = (const float*)d_in[0];
  const float* w = (const float*)d_in[1];
  const float* b = (const float*)d_in[2];
  float* out = (float*)d_out;
  dim3 grid(IMG / TILE, IMG / TILE, 2);
  pkc2d_kernel<<<grid, dim3(256), 0, stream>>>(x, w, b, out);
}

// Round 13
// 114.148 us; speedup vs baseline: 14.7601x; 1.5194x over previous
//
#include <hip/hip_runtime.h>
#include <hip/hip_bf16.h>

#define TILE 16
#define HALO 5
#define TW   26          // TILE + 2*HALO
#define NCH  16
#define NP   40
#define NSEL 16
#define IMG  256
#define XSN  (NCH * TW * TW)   // 10816 floats = 43264 B

typedef __attribute__((ext_vector_type(8))) short bf16x8;
typedef __attribute__((ext_vector_type(4))) short bf16x4;
typedef __attribute__((ext_vector_type(4))) float f32x4;

// Ring offsets in the exact order of _prf_offsets(1,4,4):
__device__ __forceinline__ constexpr int ring_dx(int p) {
  return (p < 11) ? -5 : (p < 20) ? (p - 15) : (p < 31) ? 5 : (p - 35);
}
__device__ __forceinline__ constexpr int ring_dy(int p) {
  return (p < 11) ? (p - 5) : (p < 20) ? 5 : (p < 31) ? (p - 25) : -5;
}
__device__ __forceinline__ constexpr int ring_off(int p) {
  return (ring_dx(p) + HALO) * TW + (ring_dy(p) + HALO);
}

__device__ __forceinline__ unsigned short f2bf(float f) {
  return __builtin_bit_cast(unsigned short, __float2bfloat16(f));
}

// Inline f64 exp (no libm call). Cody-Waite + deg-15 Taylor; rel err ~5e-16.
__device__ __forceinline__ float sigmoid_key(float z) {
  double x = -(double)z;
  const double LOG2E = 1.4426950408889634074;
  double t = __dmul_rn(x, LOG2E);
  const double SHIFT = 6755399441055744.0;        // 1.5*2^52
  double ts = __dadd_rn(t, SHIFT);
  double n = __dsub_rn(ts, SHIFT);
  int ni = (int)n;
  const double LN2_HI = 6.93147180369123816490e-01;
  const double LN2_LO = 1.90821492927058770002e-10;
  double r = __builtin_fma(-n, LN2_HI, x);
  r = __builtin_fma(-n, LN2_LO, r);                // |r| <= 0.34658
  double p =                 7.6471637318198164759e-13;
  p = __builtin_fma(p, r, 1.1470745597729724714e-11);
  p = __builtin_fma(p, r, 1.6059043836821614599e-10);
  p = __builtin_fma(p, r, 2.0876756987868098979e-09);
  p = __builtin_fma(p, r, 2.5052108385441718775e-08);
  p = __builtin_fma(p, r, 2.7557319223985890653e-07);
  p = __builtin_fma(p, r, 2.7557319223985892510e-06);
  p = __builtin_fma(p, r, 2.4801587301587301566e-05);
  p = __builtin_fma(p, r, 1.9841269841269841253e-04);
  p = __builtin_fma(p, r, 1.3888888888888889419e-03);
  p = __builtin_fma(p, r, 8.3333333333333332177e-03);
  p = __builtin_fma(p, r, 4.1666666666666664354e-02);
  p = __builtin_fma(p, r, 1.6666666666666665741e-01);
  p = __builtin_fma(p, r, 5.0e-01);
  p = __builtin_fma(p, r, 1.0);
  p = __builtin_fma(p, r, 1.0);
  double sc = __longlong_as_double(((long long)(1023 + ni)) << 52);
  float ef = (float)__dmul_rn(p, sc);
  return __fdiv_rn(1.0f, __fadd_rn(1.0f, ef));
}

__global__ __launch_bounds__(256, 2)
void pkc2d_kernel(const float* __restrict__ x, const float* __restrict__ w,
                  const float* __restrict__ bias, float* __restrict__ out) {
  __shared__ float xs[XSN];                 // 43264 B
  __shared__ unsigned char wsb[16384];      // w as bf16, [oc][k] XOR-swizzled
  __shared__ unsigned char dnb[16384];      // 4 waves x 64 px x 32 k x bf16

  const int tid = threadIdx.x;
  const int bz = blockIdx.z;
  const int i0 = blockIdx.y * TILE;
  const int j0 = blockIdx.x * TILE;

  // ---- stage w -> bf16 LDS, layout [oc][k] with byte^=((oc&7)<<4) swizzle ----
  {
    const float4* wsrc4 = (const float4*)w;
#pragma unroll
    for (int it = 0; it < 8; ++it) {
      float4 f = wsrc4[it * 256 + tid];
      int flat = it * 1024 + tid * 4;       // w flat index: oc*256 + k
      int oc = flat >> 8;
      int k = flat & 255;
      bf16x4 v;
      v[0] = (short)f2bf(f.x); v[1] = (short)f2bf(f.y);
      v[2] = (short)f2bf(f.z); v[3] = (short)f2bf(f.w);
      unsigned a = ((unsigned)(oc * 512 + k * 2)) ^ (unsigned)((oc & 7) << 4);
      *(bf16x4*)(wsb + a) = v;
    }
  }

  // ---- stage x tile (with zero halo) into LDS ----
  const float* xb = x + (size_t)bz * NCH * IMG * IMG;
  for (int t = tid; t < XSN; t += 256) {
    int c = t / (TW * TW);
    int rem = t - c * (TW * TW);
    int r = rem / TW;
    int col = rem - r * TW;
    int gi = i0 + r - HALO;
    int gj = j0 + col - HALO;
    float v = 0.0f;
    if ((unsigned)gi < (unsigned)IMG && (unsigned)gj < (unsigned)IMG)
      v = xb[(c * IMG + gi) * IMG + gj];
    xs[t] = v;
  }
  __syncthreads();

  const int tx = tid & (TILE - 1);
  const int ty = tid >> 4;
  const int corner = ty * TW + tx;
  const int cen = corner + HALO * TW + HALO;

  // ---- dots, c-OUTER (bit-exact np reduce order per p) ----
  float keys[NP];
#pragma unroll
  for (int p = 0; p < NP; ++p) keys[p] = 0.0f;
#pragma unroll 1
  for (int c = 0; c < NCH; ++c) {
    const float* xsc = &xs[c * (TW * TW)];
    float xcv = xsc[cen];
#pragma unroll
    for (int p = 0; p < NP; ++p)
      keys[p] = __fadd_rn(keys[p], __fmul_rn(xsc[corner + ring_off(p)], xcv));
  }

  // ---- sigmoid pass: f32 buckets via inline f64 exp ----
#pragma unroll
  for (int p = 0; p < NP; ++p) {
    keys[p] = sigmoid_key(__fmul_rn(keys[p], 0.0625f));
    if ((p & 3) == 3) __builtin_amdgcn_sched_barrier(0);
  }

  // ---- STABLE selection of 16 smallest (ties -> lower index) ----
  int soff[NSEL];
#pragma unroll
  for (int n = 0; n < NSEL; ++n) {
    float best = 3.0e38f;
    int bi = 0;
#pragma unroll
    for (int p = 0; p < NP; ++p) {
      bool better = keys[p] < best;   // strict < keeps earliest index on ties
      best = better ? keys[p] : best;
      bi   = better ? p : bi;
    }
    soff[n] = bi;
#pragma unroll
    for (int p = 0; p < NP; ++p)
      keys[p] = (p == bi) ? 3.0e38f : keys[p];
  }
#pragma unroll
  for (int n = 0; n < NSEL; ++n) {
    int b = soff[n];
    int dx = (b < 11) ? -5 : (b < 20) ? (b - 15) : (b < 31) ? 5 : (b - 35);
    int dy = (b < 11) ? (b - 5) : (b < 20) ? 5 : (b < 31) ? (b - 25) : -5;
    soff[n] = corner + (dx + HALO) * TW + (dy + HALO);
  }

  // ---- conv on MFMA: D[64px][32oc] = dn[64px][256k] x w[256k][32oc] per wave.
  // dn per K-slice of 32 (2 channels) in wave-private swizzled LDS; bf16 in,
  // f32 acc (error << 0.137 threshold). ----
  const int l = tid & 63;
  const int wv = tid >> 6;
  const unsigned dnwb = (unsigned)(wv * 4096);
  // A-frag read base: px=l&15, k-bytes (l>>4)*16, swz (l&7)<<4 (px&7==l&7)
  const unsigned aBase = dnwb + ((((l & 15) * 64) | ((l >> 4) * 16)) ^ (unsigned)((l & 7) << 4));

  float b0 = bias[l & 15];
  float b1 = bias[16 + (l & 15)];
  f32x4 acc[4][2];
#pragma unroll
  for (int m = 0; m < 4; ++m) {
    acc[m][0] = (f32x4){b0, b0, b0, b0};
    acc[m][1] = (f32x4){b1, b1, b1, b1};
  }

#pragma unroll 1
  for (int s = 0; s < 8; ++s) {
    // dn slice: channels 2s, 2s+1 -> 32 bf16 (k-local 0..31)
    float dnf[32];
#pragma unroll
    for (int cc = 0; cc < 2; ++cc) {
      const float* xsc = &xs[(2 * s + cc) * (TW * TW)];
      float xcv = xsc[cen];
#pragma unroll
      for (int n = 0; n < 16; ++n) dnf[cc * 16 + n] = xcv - xsc[soff[n]];
    }
#pragma unroll
    for (int q = 0; q < 4; ++q) {
      bf16x8 v;
#pragma unroll
      for (int e = 0; e < 8; ++e) v[e] = (short)f2bf(dnf[q * 8 + e]);
      unsigned a = dnwb + (((unsigned)((l * 64) | (q * 16))) ^ (unsigned)((l & 7) << 4));
      *(bf16x8*)(dnb + a) = v;
    }
    // fragments (same-wave LDS ordering; compiler inserts lgkmcnt)
    bf16x8 av0 = *(const bf16x8*)(dnb + aBase);
    bf16x8 av1 = *(const bf16x8*)(dnb + aBase + 1024);
    bf16x8 av2 = *(const bf16x8*)(dnb + aBase + 2048);
    bf16x8 av3 = *(const bf16x8*)(dnb + aBase + 3072);
    unsigned bb0 = ((unsigned)(((l & 15) * 512) | (s * 64) | ((l >> 4) * 16))) ^ (unsigned)((l & 7) << 4);
    unsigned bb1 = ((unsigned)(((16 + (l & 15)) * 512) | (s * 64) | ((l >> 4) * 16))) ^ (unsigned)((l & 7) << 4);
    bf16x8 bv0 = *(const bf16x8*)(wsb + bb0);
    bf16x8 bv1 = *(const bf16x8*)(wsb + bb1);
    acc[0][0] = __builtin_amdgcn_mfma_f32_16x16x32_bf16(av0, bv0, acc[0][0], 0, 0, 0);
    acc[0][1] = __builtin_amdgcn_mfma_f32_16x16x32_bf16(av0, bv1, acc[0][1], 0, 0, 0);
    acc[1][0] = __builtin_amdgcn_mfma_f32_16x16x32_bf16(av1, bv0, acc[1][0], 0, 0, 0);
    acc[1][1] = __builtin_amdgcn_mfma_f32_16x16x32_bf16(av1, bv1, acc[1][1], 0, 0, 0);
    acc[2][0] = __builtin_amdgcn_mfma_f32_16x16x32_bf16(av2, bv0, acc[2][0], 0, 0, 0);
    acc[2][1] = __builtin_amdgcn_mfma_f32_16x16x32_bf16(av2, bv1, acc[2][1], 0, 0, 0);
    acc[3][0] = __builtin_amdgcn_mfma_f32_16x16x32_bf16(av3, bv0, acc[3][0], 0, 0, 0);
    acc[3][1] = __builtin_amdgcn_mfma_f32_16x16x32_bf16(av3, bv1, acc[3][1], 0, 0, 0);
  }

  // ---- store: C/D frag (m89): col(oc)=l&15, row(px)=(l>>4)*4+j ----
  float* outb = out + (size_t)bz * 32 * IMG * IMG;
#pragma unroll
  for (int m = 0; m < 4; ++m) {
    int ii = i0 + wv * 4 + m;               // px>>4 = wv*4+m
#pragma unroll
    for (int nt = 0; nt < 2; ++nt) {
      int oc = nt * 16 + (l & 15);
      float* op = outb + (size_t)oc * IMG * IMG + (size_t)ii * IMG + j0 + ((l >> 4) * 4);
#pragma unroll
      for (int j = 0; j < 4; ++j)
        op[j] = acc[m][nt][j];
    }
  }
}

extern "C" void kernel_launch(void* const* d_in, const int* in_sizes, int n_in,
                              void* d_out, int out_size, void* d_ws, size_t ws_size,
                              hipStream_t stream) {
  const float* x = (const float*)d_in[0];
  const float* w = (const float*)d_in[1];
  const float* b = (const float*)d_in[2];
  float* out = (float*)d_out;
  dim3 grid(IMG / TILE, IMG / TILE, 2);
  pkc2d_kernel<<<grid, dim3(256), 0, stream>>>(x, w, b, out);
}